// Round 1
// baseline (669.050 us; speedup 1.0000x reference)
//
#include <hip/hip_runtime.h>
#include <cmath>

#define NTOK 32768   // 8*4096 tokens
#define EMB  2048
#define NEXP 64
#define TOPK 8
#define TB   32      // tokens per block (4 waves x 8 tokens)
#define KC   32      // K-chunk staged in LDS
#define KST  34      // LDS row stride in doubles (pad, keeps 16B align)

__global__ __launch_bounds__(256) void router_kernel(
    const float* __restrict__ X,   // [NTOK][EMB]
    const float* __restrict__ W,   // [NEXP][EMB]
    const float* __restrict__ Bv,  // [NEXP]
    float* __restrict__ out)       // probs [NTOK][64] then indices [NTOK][8] (as float)
{
    __shared__ __align__(16) double xs[TB * KST];    // x chunk, pre-converted to f64
    __shared__ __align__(16) double wt[NEXP * KST];  // W chunk, pre-converted to f64

    const int tid  = threadIdx.x;
    const int lane = tid & 63;     // lane == expert id
    const int wv   = tid >> 6;     // wave id: handles tokens wv*8 .. wv*8+7
    const int t0   = blockIdx.x * TB;

    // fp64 accumulators: 8 tokens per lane, one expert per lane
    double acc[8];
    const double bias = (double)Bv[lane];
    #pragma unroll
    for (int r = 0; r < 8; ++r) acc[r] = bias;

    for (int k0 = 0; k0 < EMB; k0 += KC) {
        // ---- stage x chunk: TB*KC = 1024 floats -> 1 float4/thread ----
        {
            const int t  = tid >> 3;          // 8 float4 per 32-float row
            const int kg = (tid & 7) << 2;
            const float4 v = *(const float4*)&X[(size_t)(t0 + t) * EMB + k0 + kg];
            double* dst = &xs[t * KST + kg];
            dst[0] = (double)v.x; dst[1] = (double)v.y;
            dst[2] = (double)v.z; dst[3] = (double)v.w;
        }
        // ---- stage W chunk: NEXP*KC = 2048 floats -> 2 float4/thread ----
        #pragma unroll
        for (int j = 0; j < 2; ++j) {
            const int f  = tid + j * 256;
            const int e  = f >> 3;
            const int kg = (f & 7) << 2;
            const float4 v = *(const float4*)&W[(size_t)e * EMB + k0 + kg];
            double* dst = &wt[e * KST + kg];
            dst[0] = (double)v.x; dst[1] = (double)v.y;
            dst[2] = (double)v.z; dst[3] = (double)v.w;
        }
        __syncthreads();

        const double* xrow = &xs[wv * 8 * KST];
        const double* wrow = &wt[lane * KST];
        #pragma unroll 4
        for (int kg = 0; kg < KC; kg += 2) {
            const double2 w2 = *(const double2*)&wrow[kg];
            #pragma unroll
            for (int r = 0; r < 8; ++r) {
                const double2 x2 = *(const double2*)&xrow[r * KST + kg];
                acc[r] = fma(w2.x, x2.x, acc[r]);
                acc[r] = fma(w2.y, x2.y, acc[r]);
            }
        }
        __syncthreads();
    }

    // ---- per-token top-8 (wave-wide, lane==expert) + masked softmax ----
    float* probs = out;                       // [NTOK][64] fp32
    float* idxo  = out + (size_t)NTOK * NEXP; // [NTOK][8] index values as fp32

    #pragma unroll
    for (int r = 0; r < 8; ++r) {
        const int t = t0 + wv * 8 + r;
        const double v = acc[r];
        bool   sel   = false;
        int    myidx = 0;      // lane i (<8) captures rank-i expert index
        double m0    = 0.0;
        float  ssum  = 0.0f;
        #pragma unroll
        for (int i = 0; i < TOPK; ++i) {
            double x = sel ? -1.0e300 : v;
            double m = x;
            #pragma unroll
            for (int off = 32; off > 0; off >>= 1) {
                double o = __shfl_xor(m, off, 64);
                m = fmax(m, o);
            }
            const unsigned long long b = __ballot(x == m);
            const int src = __ffsll(b) - 1;   // lowest lane on tie == jax stability
            if (lane == src) sel = true;
            if (lane == i)   myidx = src;
            if (i == 0)      m0 = m;
            ssum += __expf((float)(m - m0));
        }
        const float p = sel ? __expf((float)(v - m0)) / ssum : 0.0f;
        probs[(size_t)t * NEXP + lane] = p;
        if (lane < TOPK) idxo[(size_t)t * TOPK + lane] = (float)myidx;
    }
}

extern "C" void kernel_launch(void* const* d_in, const int* in_sizes, int n_in,
                              void* d_out, int out_size, void* d_ws, size_t ws_size,
                              hipStream_t stream) {
    const float* X = (const float*)d_in[0];
    const float* W = (const float*)d_in[1];
    const float* B = (const float*)d_in[2];
    float* out = (float*)d_out;
    router_kernel<<<NTOK / TB, 256, 0, stream>>>(X, W, B, out);
}

// Round 3
// 456.499 us; speedup vs baseline: 1.4656x; 1.4656x over previous
//
#include <hip/hip_runtime.h>
#include <cmath>

#define NTOK 32768   // 8*4096 tokens
#define EMB  2048
#define NEXP 64
#define TOPK 8
#define BT   64      // tokens per block (4 waves x 16 tokens)
#define KC   64      // K-chunk staged in LDS (f32)

typedef __attribute__((ext_vector_type(4))) double d4;

__global__ __launch_bounds__(256) void router_mfma(
    const float* __restrict__ X,   // [NTOK][EMB]
    const float* __restrict__ W,   // [NEXP][EMB]
    const float* __restrict__ Bv,  // [NEXP]
    float* __restrict__ out)       // probs [NTOK][64] fp32, then indices [NTOK][8] as fp32
{
    // f32 LDS tiles, column XOR-swizzled: element (row,k) stored at col k^(4*(row&7))
    __shared__ float xs[BT * KC];    // 16 KB
    __shared__ float ws[NEXP * KC];  // 16 KB

    const int tid  = threadIdx.x;
    const int lane = tid & 63;
    const int wv   = tid >> 6;        // wave: tokens wv*16 .. wv*16+15
    const int t0   = blockIdx.x * BT;
    const int eL   = lane & 15;       // A: token row; B: expert col
    const int q    = lane >> 4;       // fragment k offset
    const int sw   = 4 * (eL & 7);    // read-side XOR swizzle

    // acc[c] = D tile for experts c*16..c*16+15; init with bias (col-constant)
    d4 acc[4];
    #pragma unroll
    for (int c = 0; c < 4; ++c) {
        const double b = (double)Bv[c * 16 + eL];
        acc[c] = (d4){b, b, b, b};
    }

    for (int kc0 = 0; kc0 < EMB; kc0 += KC) {
        // ---- stage X (64x64 f32) and W (64x64 f32): 4 float4 each per thread ----
        #pragma unroll
        for (int j = 0; j < 4; ++j) {
            const int flat = tid + j * 256;    // 0..1023
            const int r    = flat >> 4;        // row 0..63
            const int a    = flat & 15;        // float4 column
            const float4 vx = *(const float4*)&X[(size_t)(t0 + r) * EMB + kc0 + 4 * a];
            const float4 vw = *(const float4*)&W[(size_t)r * EMB + kc0 + 4 * a];
            const int col = a ^ (r & 7);       // float4-granular XOR swizzle
            *(float4*)&xs[r * KC + 4 * col] = vx;
            *(float4*)&ws[r * KC + 4 * col] = vw;
        }
        __syncthreads();

        #pragma unroll
        for (int k4 = 0; k4 < KC; k4 += 4) {
            const int kk = (k4 + q) ^ sw;
            const double aF = (double)xs[(wv * 16 + eL) * KC + kk];
            #pragma unroll
            for (int c = 0; c < 4; ++c) {
                const double bF = (double)ws[(c * 16 + eL) * KC + kk];
                acc[c] = __builtin_amdgcn_mfma_f64_16x16x4f64(aF, bF, acc[c], 0, 0, 0);
            }
        }
        __syncthreads();
    }

    // ---- epilogue: top-8 + masked softmax, fully in registers/shfl ----
    // f64 MFMA D layout (CDNA dgemm, output-vector-width=1):
    //   token row = (lane>>4) + 4*reg, expert col = c*16 + (lane&15)
    float* probs = out;                        // [NTOK][64]
    float* idxo  = out + (size_t)NTOK * NEXP;  // [NTOK][8] index values as f32

    #pragma unroll
    for (int i = 0; i < 4; ++i) {
        const int T = t0 + wv * 16 + q + 4 * i;
        double v[4];
        #pragma unroll
        for (int c = 0; c < 4; ++c) v[c] = acc[c][i];

        unsigned sel = 0;
        double m0 = 0.0;
        float ssum = 0.0f;
        int myIdx = 0;
        #pragma unroll
        for (int it = 0; it < TOPK; ++it) {
            // local best among unselected candidates (c ascending => lowest index on tie)
            double bv = -1.0e300;
            int    be = 1 << 30;
            #pragma unroll
            for (int c = 0; c < 4; ++c)
                if (!((sel >> c) & 1) && v[c] > bv) { bv = v[c]; be = c * 16 + eL; }
            // 16-lane group argmax (xor 1,2,4,8 stays inside the group)
            double gv = bv; int ge = be;
            #pragma unroll
            for (int off = 1; off <= 8; off <<= 1) {
                const double ov = __shfl_xor(gv, off, 64);
                const int    oe = __shfl_xor(ge, off, 64);
                if (ov > gv || (ov == gv && oe < ge)) { gv = ov; ge = oe; }
            }
            if (it == 0) m0 = gv;
            ssum += __expf((float)(gv - m0));
            if ((ge & 15) == eL) sel |= 1u << (ge >> 4);  // owner lane marks candidate
            if (eL == it) myIdx = ge;                     // lane 'it' records rank-it index
        }
        const float inv = 1.0f / ssum;
        #pragma unroll
        for (int c = 0; c < 4; ++c) {
            const float p = ((sel >> c) & 1) ? __expf((float)(v[c] - m0)) * inv : 0.0f;
            probs[(size_t)T * NEXP + c * 16 + eL] = p;
        }
        if (eL < TOPK) idxo[(size_t)T * TOPK + eL] = (float)myIdx;
    }
}

extern "C" void kernel_launch(void* const* d_in, const int* in_sizes, int n_in,
                              void* d_out, int out_size, void* d_ws, size_t ws_size,
                              hipStream_t stream) {
    const float* X = (const float*)d_in[0];
    const float* W = (const float*)d_in[1];
    const float* B = (const float*)d_in[2];
    router_mfma<<<NTOK / BT, 256, 0, stream>>>(X, W, B, (float*)d_out);
}